// Round 10
// baseline (458.715 us; speedup 1.0000x reference)
//
#include <hip/hip_runtime.h>
#include <hip/hip_bf16.h>

// TinyCondEpsNet: out = relu([y|x|te] @ W1^T + b1) @ W2^T + b2
// B=524288, X=128, TE=32, IN=161, H=64.
// K-permutation: k 0..127 = x, 128..159 = te, 160 = y_t, 161 = const 1.0
// (folds fc1_bias), 162..191 = 0 (pad to 6 K-steps of 32).
//
// v5 DIAGNOSTIC: run the full mlp stream 3x in one dispatch (passes 0,1 ->
// ws scratch, pass 2 -> d_out; identical math each pass). Purpose: (1)
// dur_us - 378 = 2x marginal mlp cost; (2) the 3x dispatch should exceed
// the 160us fill cutoff and surface in top-5 WITH counters (VALUBusy /
// hbm_pct / Occupancy / FETCH_SIZE) -- first direct observation of the
// kernel's binding pipe. Output math unchanged.

typedef __bf16 bf16x8 __attribute__((ext_vector_type(8)));
typedef float  f32x4  __attribute__((ext_vector_type(4)));

#define NROWS   524288
#define KSTEPS  6
#define NTILES  4
#define GRID    512
#define ITERS   16          // tiles per wave per pass: 512*4*16 = 32768 tiles
#define PASSES  3
// d_ws: [0,24576) W1 frags; [24576,88576) te table; [16MB, 16MB+2MB) scratch out

static __device__ inline unsigned short f2bf(float x) {
    union { float f; unsigned u; } v; v.f = x;
    unsigned r = v.u + 0x7FFFu + ((v.u >> 16) & 1u);   // round-to-nearest-even
    return (unsigned short)(r >> 16);
}

// native casts -> v_cvt_pk_bf16_f32 pairs
static __device__ inline bf16x8 cvt8(float4 a, float4 b) {
    bf16x8 r;
    r[0] = (__bf16)a.x; r[1] = (__bf16)a.y; r[2] = (__bf16)a.z; r[3] = (__bf16)a.w;
    r[4] = (__bf16)b.x; r[5] = (__bf16)b.y; r[6] = (__bf16)b.z; r[7] = (__bf16)b.w;
    return r;
}

// ---- fused setup: W1 fragments + sinusoidal table ----
__global__ void setup_tables(const float* __restrict__ w1, const float* __restrict__ b1,
                             unsigned short* __restrict__ wf, unsigned short* __restrict__ tab) {
    int tid = blockIdx.x * blockDim.x + threadIdx.x;   // 64 blocks * 256 = 16384
    if (tid < 1536) {
        int l  = tid & 63;
        int fs = tid >> 6;          // 0..23
        int n  = fs / 6;
        int s  = fs % 6;
        int col = 16 * n + (l & 15);
        int g   = l >> 4;
        unsigned short vals[8] __attribute__((aligned(16)));
        #pragma unroll
        for (int j = 0; j < 8; ++j) {
            int k = 32 * s + 8 * g + j;
            float v;
            if      (k < 160)  v = w1[col * 161 + k + 1];
            else if (k == 160) v = w1[col * 161 + 0];
            else if (k == 161) v = b1[col];
            else               v = 0.0f;
            vals[j] = f2bf(v);
        }
        ((uint4*)wf)[tid] = *(const uint4*)vals;
    }
    if (tid < 16000) {
        int t = tid >> 4;
        int j = tid & 15;
        float freq = expf((-9.2103403719761836f * (float)j) * 0.0625f);
        float a    = (float)t * freq;
        tab[t * 32 + j]      = f2bf(sinf(a));
        tab[t * 32 + 16 + j] = f2bf(cosf(a));
    }
}

static __device__ inline int clamp_t(int tv) {
    return tv < 0 ? 0 : (tv > 999 ? 999 : tv);
}

// ---- main: persistent; 3 full passes over this wave's 16 tiles ----
__global__ __launch_bounds__(256, 2) void mlp_kernel(
    const float* __restrict__ y_t, const int* __restrict__ t, const float* __restrict__ x,
    const float* __restrict__ w2, const float* __restrict__ b2p,
    const unsigned short* __restrict__ wfrag, const unsigned short* __restrict__ tetab,
    float* __restrict__ out, float* __restrict__ scratch)
{
    const int tid = threadIdx.x;
    const int l   = tid & 63;
    const int wv  = tid >> 6;
    const int r   = l & 15;
    const int g   = l >> 4;

    float w2f[4];
    #pragma unroll
    for (int n = 0; n < NTILES; ++n) w2f[n] = w2[16 * n + r];
    const float b2 = b2p[0];
    const bf16x8* __restrict__ wfv = (const bf16x8*)wfrag;

    #pragma unroll 1
    for (int p = 0; p < PASSES; ++p) {
        float* __restrict__ outp = (p == PASSES - 1) ? out : scratch;
        long long tile = (long long)blockIdx.x * 64 + wv;

        #pragma unroll 1
        for (int i = 0; i < ITERS; ++i) {
            const long long row = tile * 16 + r;

            // ---- A fragments ----
            bf16x8 af[KSTEPS];
            const float4* __restrict__ xr = (const float4*)(x + row * 128);
            #pragma unroll
            for (int s = 0; s < 4; ++s)
                af[s] = cvt8(xr[8 * s + 2 * g], xr[8 * s + 2 * g + 1]);
            {
                int tval = clamp_t(t[row]);
                af[4] = *(const bf16x8*)(tetab + tval * 32 + 8 * g);
            }
            {
                uint4 u = make_uint4(0u, 0u, 0u, 0u);
                if (g == 0) u.x = (unsigned)f2bf(y_t[row]) | (0x3F80u << 16);
                af[5] = __builtin_bit_cast(bf16x8, u);
            }

            // ---- MFMA ----
            f32x4 acc[NTILES];
            #pragma unroll
            for (int n = 0; n < NTILES; ++n) acc[n] = (f32x4){0.f, 0.f, 0.f, 0.f};
            #pragma unroll
            for (int n = 0; n < NTILES; ++n)
                #pragma unroll
                for (int s = 0; s < KSTEPS; ++s)
                    acc[n] = __builtin_amdgcn_mfma_f32_16x16x32_bf16(
                        af[s], wfv[(n * 6 + s) * 64 + l], acc[n], 0, 0, 0);

            // ---- epilogue ----
            float4 pv4;
            float* pp = &pv4.x;
            #pragma unroll
            for (int v = 0; v < 4; ++v) {
                float pv = 0.f;
                #pragma unroll
                for (int n = 0; n < NTILES; ++n) pv += w2f[n] * fmaxf(acc[n][v], 0.f);
                pv += __shfl_xor(pv, 1);
                pv += __shfl_xor(pv, 2);
                pv += __shfl_xor(pv, 4);
                pv += __shfl_xor(pv, 8);
                pp[v] = pv + b2;
            }
            if (r == 0) {
                *(float4*)(outp + tile * 16 + 4 * g) = pv4;
            }
            tile += 4;
        }
    }
}

extern "C" void kernel_launch(void* const* d_in, const int* in_sizes, int n_in,
                              void* d_out, int out_size, void* d_ws, size_t ws_size,
                              hipStream_t stream) {
    const float* y_t = (const float*)d_in[0];
    const int*   t   = (const int*)  d_in[1];
    const float* x   = (const float*)d_in[2];
    const float* w1  = (const float*)d_in[3];
    const float* b1  = (const float*)d_in[4];
    const float* w2  = (const float*)d_in[5];
    const float* b2  = (const float*)d_in[6];

    unsigned short* wfrag   = (unsigned short*)d_ws;
    unsigned short* tetab   = wfrag + 12288;                       // 24576 B in
    float*          scratch = (float*)((char*)d_ws + (16u << 20)); // +16 MB

    setup_tables<<<64, 256, 0, stream>>>(w1, b1, wfrag, tetab);
    mlp_kernel<<<GRID, 256, 0, stream>>>(y_t, t, x, w2, b2, wfrag, tetab,
                                         (float*)d_out, scratch);
}